// Round 13
// baseline (338.042 us; speedup 1.0000x reference)
//
#include <hip/hip_runtime.h>
#include <hip/hip_bf16.h>

#define NPTS 4096
#define KNN  32

typedef __attribute__((ext_vector_type(8))) short short8;
typedef __attribute__((ext_vector_type(4))) float floatx4;

__device__ __forceinline__ unsigned short f2bf(float f) {
    unsigned u = __float_as_uint(f);
    u = (u + 0x7FFFu + ((u >> 16) & 1u)) >> 16;
    return (unsigned short)u;
}
__device__ __forceinline__ float bf2f(unsigned short v) {
    return __uint_as_float(((unsigned)v) << 16);
}

// ---------------- Kernel 0: pack points + convert weights to bf16 ------------
__global__ __launch_bounds__(256) void prep_all(
    const float* __restrict__ x, float4* __restrict__ pts4,
    const float* __restrict__ gW0, const float* __restrict__ gW1,
    const float* __restrict__ mW0, const float* __restrict__ mW1,
    unsigned short* __restrict__ Wb0, unsigned short* __restrict__ Wb1,
    unsigned short* __restrict__ Wb2, unsigned short* __restrict__ Wb3)
{
    const int blk = blockIdx.x, t = threadIdx.x;
    if (blk < 64) {
        const int i = blk * 256 + t;                 // 0..16383 = b*4096+n
        const int b = i >> 12, n = i & (NPTS - 1);
        const float* xb = x + (size_t)b * 3 * NPTS;
        const float qx = xb[n], qy = xb[NPTS + n], qz = xb[2 * NPTS + n];
        pts4[i] = make_float4(qx, qy, qz, qx * qx + qy * qy + qz * qz);
    } else {
        const int wi = (blk - 64) * 256 + t;         // 0..655359 (exact)
        float v; unsigned short* dst;
        if (wi < 98304)       { v = gW0[wi];          dst = Wb0 + wi; }
        else if (wi < 360448) { v = gW1[wi - 98304];  dst = Wb1 + (wi - 98304); }
        else if (wi < 622592) { v = mW0[wi - 360448]; dst = Wb2 + (wi - 360448); }
        else                  { v = mW1[wi - 622592]; dst = Wb3 + (wi - 622592); }
        *dst = f2bf(v);
    }
}

// ---------------- Kernel 1: exact KNN, block per query -----------------------
// Same structure as the R8/R10-passing kernel (rolled 15-iteration prefix
// search, one barrier/iter). Count path changed: per-lane accumulate
// c += (key <= thr) (v_cmp+addc, VALU) + one 6-step shfl_xor butterfly (DS
// pipe) instead of 16x popcll(ballot) -- removes the VALU 64-bit popcounts.
__global__ __launch_bounds__(256) void knn_kernel9(const float4* __restrict__ pts4,
                                                   int* __restrict__ knn_out)
{
    __shared__ unsigned sred[2][4];
    __shared__ unsigned long long C[96];
    __shared__ unsigned ccnt;

    const int t = threadIdx.x, wid = t >> 6, lane = t & 63;
    const int q = blockIdx.x, b = q >> 12, n = q & (NPTS - 1);
    const float4* P = pts4 + ((size_t)b << 12);
    const float4 s = P[n];
    const float px = s.x, py = s.y, pz = s.z, sqn = s.w;

    if (t == 0) ccnt = 0u;

    unsigned key[16];
    #pragma unroll
    for (int g = 0; g < 4; ++g) {
        float4 c0 = P[((g * 4 + 0) << 8) + t];
        float4 c1 = P[((g * 4 + 1) << 8) + t];
        float4 c2 = P[((g * 4 + 2) << 8) + t];
        float4 c3 = P[((g * 4 + 3) << 8) + t];
        float d0 = (sqn + c0.w) - 2.0f * (px * c0.x + py * c0.y + pz * c0.z);
        float d1 = (sqn + c1.w) - 2.0f * (px * c1.x + py * c1.y + pz * c1.z);
        float d2 = (sqn + c2.w) - 2.0f * (px * c2.x + py * c2.y + pz * c2.z);
        float d3 = (sqn + c3.w) - 2.0f * (px * c3.x + py * c3.y + pz * c3.z);
        unsigned u0 = __float_as_uint(d0), u1 = __float_as_uint(d1);
        unsigned u2 = __float_as_uint(d2), u3 = __float_as_uint(d3);
        key[g * 4 + 0] = (u0 & 0x80000000u) ? ~u0 : (u0 | 0x80000000u);
        key[g * 4 + 1] = (u1 & 0x80000000u) ? ~u1 : (u1 | 0x80000000u);
        key[g * 4 + 2] = (u2 & 0x80000000u) ? ~u2 : (u2 | 0x80000000u);
        key[g * 4 + 3] = (u3 & 0x80000000u) ? ~u3 : (u3 | 0x80000000u);
    }

    unsigned lo = 0x8000u, hi = 0xFF7Fu;
    for (int it = 0; it < 15; ++it) {
        const unsigned mid = (lo + hi) >> 1;
        const unsigned thr = (mid << 16) | 0xFFFFu;
        unsigned c = 0;
        #pragma unroll
        for (int r = 0; r < 16; ++r)
            c += (key[r] <= thr) ? 1u : 0u;        // per-lane, no popcount
        c += __shfl_xor(c, 1, 64);
        c += __shfl_xor(c, 2, 64);
        c += __shfl_xor(c, 4, 64);
        c += __shfl_xor(c, 8, 64);
        c += __shfl_xor(c, 16, 64);
        c += __shfl_xor(c, 32, 64);                 // wave sum in every lane
        if (lane == 0) sred[it & 1][wid] = c;
        __syncthreads();
        const unsigned g = sred[it & 1][0] + sred[it & 1][1] +
                           sred[it & 1][2] + sred[it & 1][3];
        if (g >= 33u) hi = mid; else lo = mid + 1u;
    }
    const unsigned thrF = (lo << 16) | 0xFFFFu;

    #pragma unroll
    for (int r = 0; r < 16; ++r) {
        if (key[r] <= thrF) {
            unsigned p = atomicAdd(&ccnt, 1u);
            if (p < 96u)
                C[p] = ((unsigned long long)key[r] << 32) |
                       (unsigned)((r << 8) + t);
        }
    }
    __syncthreads();

    int nc = (int)ccnt; if (nc > 96) nc = 96;
    if (t < nc) {
        const unsigned long long me = C[t];
        int rank = 0;
        for (int j = 0; j < nc; ++j) rank += (C[j] < me) ? 1 : 0;
        if (rank >= 1 && rank <= KNN)
            knn_out[(size_t)q * KNN + (rank - 1)] = (int)(me & 0xFFFFFFFFu);
    }
}

// ---------------- Kernel 2: per-point 3-layer MLP -> F bf16 [b][n][384] ------
__global__ __launch_bounds__(256) void pointmlp_kernel(
    const float* __restrict__ x,
    const float* __restrict__ sW0, const float* __restrict__ sb0,
    const float* __restrict__ sW1, const float* __restrict__ sb1,
    const float* __restrict__ sW2, const float* __restrict__ sb2,
    unsigned short* __restrict__ F)
{
    __shared__ __align__(16) float BUF[8192];
    __shared__ __align__(16) float h1s[64 * 36];
    __shared__ float b1s[64];
    __shared__ float b2s[128];
    __shared__ float pts[3 * 33];

    const int t = threadIdx.x;
    const int s = blockIdx.y;
    const int tile = blockIdx.x;
    const int b = tile >> 7;
    const int j0 = (tile & 127) << 5;
    const float* xb = x + (size_t)b * 3 * NPTS;

    if (t < 192) BUF[t] = sW0[s * 192 + t];
    else if (t < 256) BUF[t] = sb0[s * 64 + (t - 192)];
    if (t < 64) b1s[t] = sb1[s * 64 + t];
    if (t < 128) b2s[t] = sb2[s * 128 + t];
    if (t < 96) { int c = t >> 5, p = t & 31; pts[c * 33 + p] = xb[c * NPTS + j0 + p]; }
    {
        const float* W1 = sW1 + (size_t)s * 4096;
        int o = t & 63, q = t >> 6;
        #pragma unroll
        for (int r = 0; r < 4; ++r) {
            float4 w = *(const float4*)(W1 + o * 64 + q * 16 + r * 4);
            int i = q * 16 + r * 4;
            BUF[256 + (i + 0) * 64 + o] = w.x;
            BUF[256 + (i + 1) * 64 + o] = w.y;
            BUF[256 + (i + 2) * 64 + o] = w.z;
            BUF[256 + (i + 3) * 64 + o] = w.w;
        }
    }
    __syncthreads();
    const int o = t & 63, pg = t >> 6;
    float* h0 = BUF + 4352;
    {
        float w0 = BUF[o * 3], w1 = BUF[o * 3 + 1], w2 = BUF[o * 3 + 2], bb = BUF[192 + o];
        #pragma unroll
        for (int p = 0; p < 8; ++p) {
            int pp = pg * 8 + p;
            float a = bb + w0 * pts[pp] + w1 * pts[33 + pp] + w2 * pts[66 + pp];
            h0[o * 36 + pp] = fmaxf(a, 0.0f);
        }
    }
    __syncthreads();
    {
        float acc[8];
        #pragma unroll
        for (int p = 0; p < 8; ++p) acc[p] = b1s[o];
        for (int i = 0; i < 64; ++i) {
            float w = BUF[256 + i * 64 + o];
            float4 ha = *(const float4*)&h0[i * 36 + pg * 8];
            float4 hb = *(const float4*)&h0[i * 36 + pg * 8 + 4];
            acc[0] += w * ha.x; acc[1] += w * ha.y; acc[2] += w * ha.z; acc[3] += w * ha.w;
            acc[4] += w * hb.x; acc[5] += w * hb.y; acc[6] += w * hb.z; acc[7] += w * hb.w;
        }
        #pragma unroll
        for (int p = 0; p < 8; ++p) h1s[o * 36 + pg * 8 + p] = fmaxf(acc[p], 0.0f);
    }
    __syncthreads();
    {
        const float* W2 = sW2 + (size_t)s * 8192;
        int o2 = t & 127, q = t >> 7;
        #pragma unroll
        for (int r = 0; r < 8; ++r) {
            float4 w = *(const float4*)(W2 + o2 * 64 + q * 32 + r * 4);
            int i = q * 32 + r * 4;
            BUF[(i + 0) * 128 + o2] = w.x;
            BUF[(i + 1) * 128 + o2] = w.y;
            BUF[(i + 2) * 128 + o2] = w.z;
            BUF[(i + 3) * 128 + o2] = w.w;
        }
    }
    __syncthreads();
    {
        int o2 = t & 127, ph = t >> 7;
        float acc[16];
        #pragma unroll
        for (int p = 0; p < 16; ++p) acc[p] = b2s[o2];
        for (int i = 0; i < 64; ++i) {
            float w = BUF[i * 128 + o2];
            float4 ha = *(const float4*)&h1s[i * 36 + ph * 16];
            float4 hb = *(const float4*)&h1s[i * 36 + ph * 16 + 4];
            float4 hc = *(const float4*)&h1s[i * 36 + ph * 16 + 8];
            float4 hd = *(const float4*)&h1s[i * 36 + ph * 16 + 12];
            acc[0]  += w * ha.x; acc[1]  += w * ha.y; acc[2]  += w * ha.z; acc[3]  += w * ha.w;
            acc[4]  += w * hb.x; acc[5]  += w * hb.y; acc[6]  += w * hb.z; acc[7]  += w * hb.w;
            acc[8]  += w * hc.x; acc[9]  += w * hc.y; acc[10] += w * hc.z; acc[11] += w * hc.w;
            acc[12] += w * hd.x; acc[13] += w * hd.y; acc[14] += w * hd.z; acc[15] += w * hd.w;
        }
        #pragma unroll
        for (int p = 0; p < 16; ++p) {
            int j = j0 + ph * 16 + p;
            F[((size_t)b * NPTS + j) * 384 + s * 128 + o2] = f2bf(fmaxf(acc[p], 0.0f));
        }
    }
}

// ---------------- Kernel 3: gather-max (bf16 in/out), point [b][n][384] ------
__global__ __launch_bounds__(384) void maxgather_bf16(
    const unsigned short* __restrict__ F, const int* __restrict__ knn,
    unsigned short* __restrict__ pt)
{
    __shared__ int idxS[KNN];
    const int q = blockIdx.x;            // b*4096 + n
    const int b = q >> 12;
    const int t = threadIdx.x;           // channel 0..383
    if (t < KNN) idxS[t] = knn[(size_t)q * KNN + t];
    __syncthreads();
    const unsigned short* Fb = F + (size_t)b * NPTS * 384;
    unsigned short m = 0;
    #pragma unroll 8
    for (int k = 0; k < KNN; ++k) {
        unsigned short v = Fb[(size_t)idxS[k] * 384 + t];
        m = (v > m) ? v : m;
    }
    pt[(size_t)q * 384 + t] = m;
}

// ---------------- Kernel 4: bf16 MFMA GEMM + bias + relu (R10-passing) -------
// C[b] = relu(Wb[M][K] (bf16) * B^T[b][n][K] (bf16) + bias), 128x128 tile,
// 4 waves. OUT_FP32=0: out bf16 [b][n][M]; OUT_FP32=1: fp32 [b][m][4096].
// DO_ROWMAX=1: gfeat[b][m] = max_n out via LDS+global atomicMax (values >= 0).
template<int OUT_FP32, int DO_ROWMAX>
__global__ __launch_bounds__(256) void gemm_bf16(
    const unsigned short* __restrict__ Wb, const unsigned short* __restrict__ Bt,
    const float* __restrict__ bias, void* __restrict__ outp,
    float* __restrict__ gfeat, int M, int K)
{
    __shared__ __align__(16) unsigned short As[128 * 40]; // [m][k] pad 40
    __shared__ __align__(16) unsigned short Bs[128 * 40]; // [n][k] pad 40
    __shared__ float biasS[128];
    __shared__ int redI[128];

    const int t = threadIdx.x;
    const int b = blockIdx.z;
    const int m0 = blockIdx.x * 128;
    const int n0 = blockIdx.y * 128;
    if (t < 128) biasS[t] = bias[m0 + t];
    if (DO_ROWMAX && t < 128) redI[t] = 0;

    const int wave = t >> 6, lane = t & 63, quad = lane >> 4, l15 = lane & 15;
    const int wr = wave >> 1, wc = wave & 1;

    const int am = t & 127, akh = t >> 7;            // A: row m, k-half (16)
    const unsigned short* Wp = Wb + (size_t)(m0 + am) * K + akh * 16;
    const int bn = t >> 2, bq = t & 3;               // B: 4 thr per n-row
    const unsigned short* Bp = Bt + ((size_t)b * NPTS + n0) * K;

    floatx4 acc[16];
    #pragma unroll
    for (int i = 0; i < 16; ++i) acc[i] = (floatx4){0.f, 0.f, 0.f, 0.f};

    const int nk = K >> 5;
    for (int kt = 0; kt < nk; ++kt) {
        const int k0 = kt << 5;
        uint4 av0 = *(const uint4*)(Wp + k0);        // 8 bf16
        uint4 av1 = *(const uint4*)(Wp + k0 + 8);    // 8 bf16
        uint4 bv0 = *(const uint4*)(Bp + (size_t)bn * K + k0 + bq * 8);
        uint4 bv1 = *(const uint4*)(Bp + (size_t)(bn + 64) * K + k0 + bq * 8);
        __syncthreads();
        {
            uint4* dst = (uint4*)&As[am * 40 + akh * 16];
            dst[0] = av0;
            dst[1] = av1;
            *(uint4*)&Bs[bn * 40 + bq * 8] = bv0;
            *(uint4*)&Bs[(bn + 64) * 40 + bq * 8] = bv1;
        }
        __syncthreads();
        short8 af[4], bfv[4];
        #pragma unroll
        for (int i = 0; i < 4; ++i)
            af[i] = *(const short8*)&As[(wr * 64 + i * 16 + l15) * 40 + quad * 8];
        #pragma unroll
        for (int j = 0; j < 4; ++j)
            bfv[j] = *(const short8*)&Bs[(wc * 64 + j * 16 + l15) * 40 + quad * 8];
        #pragma unroll
        for (int i = 0; i < 4; ++i)
            #pragma unroll
            for (int j = 0; j < 4; ++j)
                acc[i * 4 + j] = __builtin_amdgcn_mfma_f32_16x16x32_bf16(
                    af[i], bfv[j], acc[i * 4 + j], 0, 0, 0);
    }

    #pragma unroll
    for (int i = 0; i < 4; ++i) {
        const int mbase = wr * 64 + i * 16 + quad * 4;   // local m rows
        float rm0 = 0.f, rm1 = 0.f, rm2 = 0.f, rm3 = 0.f;
        #pragma unroll
        for (int j = 0; j < 4; ++j) {
            const int n = n0 + wc * 64 + j * 16 + l15;
            float v0 = fmaxf(acc[i * 4 + j][0] + biasS[mbase + 0], 0.f);
            float v1 = fmaxf(acc[i * 4 + j][1] + biasS[mbase + 1], 0.f);
            float v2 = fmaxf(acc[i * 4 + j][2] + biasS[mbase + 2], 0.f);
            float v3 = fmaxf(acc[i * 4 + j][3] + biasS[mbase + 3], 0.f);
            if (DO_ROWMAX) {
                rm0 = fmaxf(rm0, v0); rm1 = fmaxf(rm1, v1);
                rm2 = fmaxf(rm2, v2); rm3 = fmaxf(rm3, v3);
            }
            if (OUT_FP32) {
                float* o = (float*)outp + ((size_t)b * M + m0 + mbase) * NPTS + n;
                o[0 * NPTS] = v0; o[1 * NPTS] = v1; o[2 * NPTS] = v2; o[3 * NPTS] = v3;
            } else {
                ushort4 pk;
                pk.x = f2bf(v0); pk.y = f2bf(v1); pk.z = f2bf(v2); pk.w = f2bf(v3);
                *(ushort4*)((unsigned short*)outp +
                            ((size_t)b * NPTS + n) * M + m0 + mbase) = pk;
            }
        }
        if (DO_ROWMAX) {   // values >= 0 -> int-bit compare == float compare
            atomicMax(&redI[mbase + 0], __float_as_int(rm0));
            atomicMax(&redI[mbase + 1], __float_as_int(rm1));
            atomicMax(&redI[mbase + 2], __float_as_int(rm2));
            atomicMax(&redI[mbase + 3], __float_as_int(rm3));
        }
    }
    if (DO_ROWMAX) {
        __syncthreads();
        if (t < 128)       // d_out zeroed before launch; values >= 0 -> safe
            atomicMax((int*)&gfeat[(size_t)b * 1024 + m0 + t], redI[t]);
    }
}

extern "C" void kernel_launch(void* const* d_in, const int* in_sizes, int n_in,
                              void* d_out, int out_size, void* d_ws, size_t ws_size,
                              hipStream_t stream)
{
    const float* x   = (const float*)d_in[0];
    const float* sW0 = (const float*)d_in[1];
    const float* sb0 = (const float*)d_in[2];
    const float* sW1 = (const float*)d_in[3];
    const float* sb1 = (const float*)d_in[4];
    const float* sW2 = (const float*)d_in[5];
    const float* sb2 = (const float*)d_in[6];
    const float* gW0 = (const float*)d_in[7];
    const float* gb0 = (const float*)d_in[8];
    const float* gW1 = (const float*)d_in[9];
    const float* gb1 = (const float*)d_in[10];
    const float* mW0 = (const float*)d_in[11];
    const float* mb0 = (const float*)d_in[12];
    const float* mW1 = (const float*)d_in[13];
    const float* mb1 = (const float*)d_in[14];
    float* outp = (float*)d_out;

    char* ws = (char*)d_ws;
    int*            idx     = (int*)(ws);                        // 2 MB
    float4*         pts4    = (float4*)(ws + 2097152u);          // 256 KB
    unsigned short* Wb0     = (unsigned short*)(ws + 2359296u);  // 192 KB  gW0 bf16
    unsigned short* Wb1     = (unsigned short*)(ws + 2555904u);  // 512 KB  gW1 bf16
    unsigned short* Wb2     = (unsigned short*)(ws + 3080192u);  // 512 KB  mW0 bf16
    unsigned short* Wb3     = (unsigned short*)(ws + 3604480u);  // 64 KB   mW1 bf16
    unsigned short* F       = (unsigned short*)(ws + 4194304u);  // 12.6 MB [b][n][384] bf16
    unsigned short* point_t = (unsigned short*)(ws + 18874368u); // 12.6 MB [b][n][384] bf16
    unsigned short* gf0t    = (unsigned short*)(ws + 33554432u); // 8.4 MB  [b][n][256] bf16
    unsigned short* gft     = (unsigned short*)(ws + 50331648u); // 33.6 MB [b][n][1024] bf16
    unsigned short* msf0t   = (unsigned short*)(ws + 100663296u);// 8.4 MB  [b][n][256] bf16

    prep_all<<<dim3(2624), dim3(256), 0, stream>>>(
        x, pts4, gW0, gW1, mW0, mW1, Wb0, Wb1, Wb2, Wb3);
    knn_kernel9<<<dim3(16384), dim3(256), 0, stream>>>(pts4, idx);
    pointmlp_kernel<<<dim3(512, 3), dim3(256), 0, stream>>>(
        x, sW0, sb0, sW1, sb1, sW2, sb2, F);
    maxgather_bf16<<<dim3(16384), dim3(384), 0, stream>>>(F, idx, point_t);
    gemm_bf16<0, 0><<<dim3(2, 32, 4), dim3(256), 0, stream>>>(
        Wb0, point_t, gb0, gf0t, nullptr, 256, 384);
    gemm_bf16<0, 1><<<dim3(8, 32, 4), dim3(256), 0, stream>>>(
        Wb1, gf0t, gb1, gft, outp, 1024, 256);
    gemm_bf16<0, 0><<<dim3(2, 32, 4), dim3(256), 0, stream>>>(
        Wb2, gft, mb0, msf0t, nullptr, 256, 1024);
    gemm_bf16<1, 0><<<dim3(1, 32, 4), dim3(256), 0, stream>>>(
        Wb3, msf0t, mb1, outp + 4096, nullptr, 128, 256);
}

// Round 14
// 300.634 us; speedup vs baseline: 1.1244x; 1.1244x over previous
//
#include <hip/hip_runtime.h>
#include <hip/hip_bf16.h>

#define NPTS 4096
#define KNN  32

typedef __attribute__((ext_vector_type(8))) short short8;
typedef __attribute__((ext_vector_type(4))) float floatx4;

__device__ __forceinline__ unsigned short f2bf(float f) {
    unsigned u = __float_as_uint(f);
    u = (u + 0x7FFFu + ((u >> 16) & 1u)) >> 16;
    return (unsigned short)u;
}
__device__ __forceinline__ float bf2f(unsigned short v) {
    return __uint_as_float(((unsigned)v) << 16);
}

// ---------------- Kernel 0: pack points + convert weights to bf16 ------------
__global__ __launch_bounds__(256) void prep_all(
    const float* __restrict__ x, float4* __restrict__ pts4,
    const float* __restrict__ gW0, const float* __restrict__ gW1,
    const float* __restrict__ mW0, const float* __restrict__ mW1,
    unsigned short* __restrict__ Wb0, unsigned short* __restrict__ Wb1,
    unsigned short* __restrict__ Wb2, unsigned short* __restrict__ Wb3)
{
    const int blk = blockIdx.x, t = threadIdx.x;
    if (blk < 64) {
        const int i = blk * 256 + t;                 // 0..16383 = b*4096+n
        const int b = i >> 12, n = i & (NPTS - 1);
        const float* xb = x + (size_t)b * 3 * NPTS;
        const float qx = xb[n], qy = xb[NPTS + n], qz = xb[2 * NPTS + n];
        pts4[i] = make_float4(qx, qy, qz, qx * qx + qy * qy + qz * qz);
    } else {
        const int wi = (blk - 64) * 256 + t;         // 0..655359 (exact)
        float v; unsigned short* dst;
        if (wi < 98304)       { v = gW0[wi];          dst = Wb0 + wi; }
        else if (wi < 360448) { v = gW1[wi - 98304];  dst = Wb1 + (wi - 98304); }
        else if (wi < 622592) { v = mW0[wi - 360448]; dst = Wb2 + (wi - 360448); }
        else                  { v = mW1[wi - 622592]; dst = Wb3 + (wi - 622592); }
        *dst = f2bf(v);
    }
}

// ---------------- Kernel 1: exact KNN, block per query -----------------------
// R8/R10-passing shape (rolled fixed-trip ballot+popcll loop, 1 barrier/iter),
// now searching the 9-bit key prefix (sign + full exponent): positive-key
// prefixes span [0x100, 0x1FE] -> width 255 -> FIXED 8 iterations to width 1.
// Final bucket = one exponent octave of d^2 -> expected candidate count
// ~33*2^1.5 ~ 93; collect bound 192. Collected set {key <= (V<<23)|0x7FFFFF}
// is a superset of the top-33; exact (key,idx) parallel rank; ranks 1..32
// emitted (rank 0 = self dropped). Matches jax top_k incl. tie order.
__global__ __launch_bounds__(256) void knn_kernel10(const float4* __restrict__ pts4,
                                                    int* __restrict__ knn_out)
{
    __shared__ unsigned sred[2][4];
    __shared__ unsigned long long C[192];
    __shared__ unsigned ccnt;

    const int t = threadIdx.x, wid = t >> 6, lane = t & 63;
    const int q = blockIdx.x, b = q >> 12, n = q & (NPTS - 1);
    const float4* P = pts4 + ((size_t)b << 12);
    const float4 s = P[n];
    const float px = s.x, py = s.y, pz = s.z, sqn = s.w;

    if (t == 0) ccnt = 0u;

    unsigned key[16];
    #pragma unroll
    for (int g = 0; g < 4; ++g) {
        float4 c0 = P[((g * 4 + 0) << 8) + t];
        float4 c1 = P[((g * 4 + 1) << 8) + t];
        float4 c2 = P[((g * 4 + 2) << 8) + t];
        float4 c3 = P[((g * 4 + 3) << 8) + t];
        float d0 = (sqn + c0.w) - 2.0f * (px * c0.x + py * c0.y + pz * c0.z);
        float d1 = (sqn + c1.w) - 2.0f * (px * c1.x + py * c1.y + pz * c1.z);
        float d2 = (sqn + c2.w) - 2.0f * (px * c2.x + py * c2.y + pz * c2.z);
        float d3 = (sqn + c3.w) - 2.0f * (px * c3.x + py * c3.y + pz * c3.z);
        unsigned u0 = __float_as_uint(d0), u1 = __float_as_uint(d1);
        unsigned u2 = __float_as_uint(d2), u3 = __float_as_uint(d3);
        key[g * 4 + 0] = (u0 & 0x80000000u) ? ~u0 : (u0 | 0x80000000u);
        key[g * 4 + 1] = (u1 & 0x80000000u) ? ~u1 : (u1 | 0x80000000u);
        key[g * 4 + 2] = (u2 & 0x80000000u) ? ~u2 : (u2 | 0x80000000u);
        key[g * 4 + 3] = (u3 & 0x80000000u) ? ~u3 : (u3 | 0x80000000u);
    }

    // fixed 8-iteration search on 9-bit prefix; rolled loop, 1 barrier/iter
    unsigned lo = 0x100u, hi = 0x1FEu;
    for (int it = 0; it < 8; ++it) {
        const unsigned mid = (lo + hi) >> 1;
        const unsigned thr = (mid << 23) | 0x7FFFFFu;
        unsigned c = 0;
        #pragma unroll
        for (int r = 0; r < 16; ++r)
            c += (unsigned)__popcll(__ballot(key[r] <= thr));
        if (lane == 0) sred[it & 1][wid] = c;
        __syncthreads();
        const unsigned g = sred[it & 1][0] + sred[it & 1][1] +
                           sred[it & 1][2] + sred[it & 1][3];
        if (g >= 33u) hi = mid; else lo = mid + 1u;
    }
    const unsigned thrF = (lo << 23) | 0x7FFFFFu;   // lo == hi == V

    #pragma unroll
    for (int r = 0; r < 16; ++r) {
        if (key[r] <= thrF) {
            unsigned p = atomicAdd(&ccnt, 1u);
            if (p < 192u)
                C[p] = ((unsigned long long)key[r] << 32) |
                       (unsigned)((r << 8) + t);
        }
    }
    __syncthreads();

    int nc = (int)ccnt; if (nc > 192) nc = 192;
    if (t < nc) {
        const unsigned long long me = C[t];
        int rank = 0;
        for (int j = 0; j < nc; ++j) rank += (C[j] < me) ? 1 : 0;
        if (rank >= 1 && rank <= KNN)
            knn_out[(size_t)q * KNN + (rank - 1)] = (int)(me & 0xFFFFFFFFu);
    }
}

// ---------------- Kernel 2: per-point 3-layer MLP -> F bf16 [b][n][384] ------
__global__ __launch_bounds__(256) void pointmlp_kernel(
    const float* __restrict__ x,
    const float* __restrict__ sW0, const float* __restrict__ sb0,
    const float* __restrict__ sW1, const float* __restrict__ sb1,
    const float* __restrict__ sW2, const float* __restrict__ sb2,
    unsigned short* __restrict__ F)
{
    __shared__ __align__(16) float BUF[8192];
    __shared__ __align__(16) float h1s[64 * 36];
    __shared__ float b1s[64];
    __shared__ float b2s[128];
    __shared__ float pts[3 * 33];

    const int t = threadIdx.x;
    const int s = blockIdx.y;
    const int tile = blockIdx.x;
    const int b = tile >> 7;
    const int j0 = (tile & 127) << 5;
    const float* xb = x + (size_t)b * 3 * NPTS;

    if (t < 192) BUF[t] = sW0[s * 192 + t];
    else if (t < 256) BUF[t] = sb0[s * 64 + (t - 192)];
    if (t < 64) b1s[t] = sb1[s * 64 + t];
    if (t < 128) b2s[t] = sb2[s * 128 + t];
    if (t < 96) { int c = t >> 5, p = t & 31; pts[c * 33 + p] = xb[c * NPTS + j0 + p]; }
    {
        const float* W1 = sW1 + (size_t)s * 4096;
        int o = t & 63, q = t >> 6;
        #pragma unroll
        for (int r = 0; r < 4; ++r) {
            float4 w = *(const float4*)(W1 + o * 64 + q * 16 + r * 4);
            int i = q * 16 + r * 4;
            BUF[256 + (i + 0) * 64 + o] = w.x;
            BUF[256 + (i + 1) * 64 + o] = w.y;
            BUF[256 + (i + 2) * 64 + o] = w.z;
            BUF[256 + (i + 3) * 64 + o] = w.w;
        }
    }
    __syncthreads();
    const int o = t & 63, pg = t >> 6;
    float* h0 = BUF + 4352;
    {
        float w0 = BUF[o * 3], w1 = BUF[o * 3 + 1], w2 = BUF[o * 3 + 2], bb = BUF[192 + o];
        #pragma unroll
        for (int p = 0; p < 8; ++p) {
            int pp = pg * 8 + p;
            float a = bb + w0 * pts[pp] + w1 * pts[33 + pp] + w2 * pts[66 + pp];
            h0[o * 36 + pp] = fmaxf(a, 0.0f);
        }
    }
    __syncthreads();
    {
        float acc[8];
        #pragma unroll
        for (int p = 0; p < 8; ++p) acc[p] = b1s[o];
        for (int i = 0; i < 64; ++i) {
            float w = BUF[256 + i * 64 + o];
            float4 ha = *(const float4*)&h0[i * 36 + pg * 8];
            float4 hb = *(const float4*)&h0[i * 36 + pg * 8 + 4];
            acc[0] += w * ha.x; acc[1] += w * ha.y; acc[2] += w * ha.z; acc[3] += w * ha.w;
            acc[4] += w * hb.x; acc[5] += w * hb.y; acc[6] += w * hb.z; acc[7] += w * hb.w;
        }
        #pragma unroll
        for (int p = 0; p < 8; ++p) h1s[o * 36 + pg * 8 + p] = fmaxf(acc[p], 0.0f);
    }
    __syncthreads();
    {
        const float* W2 = sW2 + (size_t)s * 8192;
        int o2 = t & 127, q = t >> 7;
        #pragma unroll
        for (int r = 0; r < 8; ++r) {
            float4 w = *(const float4*)(W2 + o2 * 64 + q * 32 + r * 4);
            int i = q * 32 + r * 4;
            BUF[(i + 0) * 128 + o2] = w.x;
            BUF[(i + 1) * 128 + o2] = w.y;
            BUF[(i + 2) * 128 + o2] = w.z;
            BUF[(i + 3) * 128 + o2] = w.w;
        }
    }
    __syncthreads();
    {
        int o2 = t & 127, ph = t >> 7;
        float acc[16];
        #pragma unroll
        for (int p = 0; p < 16; ++p) acc[p] = b2s[o2];
        for (int i = 0; i < 64; ++i) {
            float w = BUF[i * 128 + o2];
            float4 ha = *(const float4*)&h1s[i * 36 + ph * 16];
            float4 hb = *(const float4*)&h1s[i * 36 + ph * 16 + 4];
            float4 hc = *(const float4*)&h1s[i * 36 + ph * 16 + 8];
            float4 hd = *(const float4*)&h1s[i * 36 + ph * 16 + 12];
            acc[0]  += w * ha.x; acc[1]  += w * ha.y; acc[2]  += w * ha.z; acc[3]  += w * ha.w;
            acc[4]  += w * hb.x; acc[5]  += w * hb.y; acc[6]  += w * hb.z; acc[7]  += w * hb.w;
            acc[8]  += w * hc.x; acc[9]  += w * hc.y; acc[10] += w * hc.z; acc[11] += w * hc.w;
            acc[12] += w * hd.x; acc[13] += w * hd.y; acc[14] += w * hd.z; acc[15] += w * hd.w;
        }
        #pragma unroll
        for (int p = 0; p < 16; ++p) {
            int j = j0 + ph * 16 + p;
            F[((size_t)b * NPTS + j) * 384 + s * 128 + o2] = f2bf(fmaxf(acc[p], 0.0f));
        }
    }
}

// ---------------- Kernel 3: gather-max (bf16 in/out), point [b][n][384] ------
__global__ __launch_bounds__(384) void maxgather_bf16(
    const unsigned short* __restrict__ F, const int* __restrict__ knn,
    unsigned short* __restrict__ pt)
{
    __shared__ int idxS[KNN];
    const int q = blockIdx.x;            // b*4096 + n
    const int b = q >> 12;
    const int t = threadIdx.x;           // channel 0..383
    if (t < KNN) idxS[t] = knn[(size_t)q * KNN + t];
    __syncthreads();
    const unsigned short* Fb = F + (size_t)b * NPTS * 384;
    unsigned short m = 0;
    #pragma unroll 8
    for (int k = 0; k < KNN; ++k) {
        unsigned short v = Fb[(size_t)idxS[k] * 384 + t];
        m = (v > m) ? v : m;
    }
    pt[(size_t)q * 384 + t] = m;
}

// ---------------- Kernel 4: bf16 MFMA GEMM + bias + relu (R10-passing) -------
template<int OUT_FP32, int DO_ROWMAX>
__global__ __launch_bounds__(256) void gemm_bf16(
    const unsigned short* __restrict__ Wb, const unsigned short* __restrict__ Bt,
    const float* __restrict__ bias, void* __restrict__ outp,
    float* __restrict__ gfeat, int M, int K)
{
    __shared__ __align__(16) unsigned short As[128 * 40]; // [m][k] pad 40
    __shared__ __align__(16) unsigned short Bs[128 * 40]; // [n][k] pad 40
    __shared__ float biasS[128];
    __shared__ int redI[128];

    const int t = threadIdx.x;
    const int b = blockIdx.z;
    const int m0 = blockIdx.x * 128;
    const int n0 = blockIdx.y * 128;
    if (t < 128) biasS[t] = bias[m0 + t];
    if (DO_ROWMAX && t < 128) redI[t] = 0;

    const int wave = t >> 6, lane = t & 63, quad = lane >> 4, l15 = lane & 15;
    const int wr = wave >> 1, wc = wave & 1;

    const int am = t & 127, akh = t >> 7;            // A: row m, k-half (16)
    const unsigned short* Wp = Wb + (size_t)(m0 + am) * K + akh * 16;
    const int bn = t >> 2, bq = t & 3;               // B: 4 thr per n-row
    const unsigned short* Bp = Bt + ((size_t)b * NPTS + n0) * K;

    floatx4 acc[16];
    #pragma unroll
    for (int i = 0; i < 16; ++i) acc[i] = (floatx4){0.f, 0.f, 0.f, 0.f};

    const int nk = K >> 5;
    for (int kt = 0; kt < nk; ++kt) {
        const int k0 = kt << 5;
        uint4 av0 = *(const uint4*)(Wp + k0);        // 8 bf16
        uint4 av1 = *(const uint4*)(Wp + k0 + 8);    // 8 bf16
        uint4 bv0 = *(const uint4*)(Bp + (size_t)bn * K + k0 + bq * 8);
        uint4 bv1 = *(const uint4*)(Bp + (size_t)(bn + 64) * K + k0 + bq * 8);
        __syncthreads();
        {
            uint4* dst = (uint4*)&As[am * 40 + akh * 16];
            dst[0] = av0;
            dst[1] = av1;
            *(uint4*)&Bs[bn * 40 + bq * 8] = bv0;
            *(uint4*)&Bs[(bn + 64) * 40 + bq * 8] = bv1;
        }
        __syncthreads();
        short8 af[4], bfv[4];
        #pragma unroll
        for (int i = 0; i < 4; ++i)
            af[i] = *(const short8*)&As[(wr * 64 + i * 16 + l15) * 40 + quad * 8];
        #pragma unroll
        for (int j = 0; j < 4; ++j)
            bfv[j] = *(const short8*)&Bs[(wc * 64 + j * 16 + l15) * 40 + quad * 8];
        #pragma unroll
        for (int i = 0; i < 4; ++i)
            #pragma unroll
            for (int j = 0; j < 4; ++j)
                acc[i * 4 + j] = __builtin_amdgcn_mfma_f32_16x16x32_bf16(
                    af[i], bfv[j], acc[i * 4 + j], 0, 0, 0);
    }

    #pragma unroll
    for (int i = 0; i < 4; ++i) {
        const int mbase = wr * 64 + i * 16 + quad * 4;   // local m rows
        float rm0 = 0.f, rm1 = 0.f, rm2 = 0.f, rm3 = 0.f;
        #pragma unroll
        for (int j = 0; j < 4; ++j) {
            const int n = n0 + wc * 64 + j * 16 + l15;
            float v0 = fmaxf(acc[i * 4 + j][0] + biasS[mbase + 0], 0.f);
            float v1 = fmaxf(acc[i * 4 + j][1] + biasS[mbase + 1], 0.f);
            float v2 = fmaxf(acc[i * 4 + j][2] + biasS[mbase + 2], 0.f);
            float v3 = fmaxf(acc[i * 4 + j][3] + biasS[mbase + 3], 0.f);
            if (DO_ROWMAX) {
                rm0 = fmaxf(rm0, v0); rm1 = fmaxf(rm1, v1);
                rm2 = fmaxf(rm2, v2); rm3 = fmaxf(rm3, v3);
            }
            if (OUT_FP32) {
                float* o = (float*)outp + ((size_t)b * M + m0 + mbase) * NPTS + n;
                o[0 * NPTS] = v0; o[1 * NPTS] = v1; o[2 * NPTS] = v2; o[3 * NPTS] = v3;
            } else {
                ushort4 pk;
                pk.x = f2bf(v0); pk.y = f2bf(v1); pk.z = f2bf(v2); pk.w = f2bf(v3);
                *(ushort4*)((unsigned short*)outp +
                            ((size_t)b * NPTS + n) * M + m0 + mbase) = pk;
            }
        }
        if (DO_ROWMAX) {   // values >= 0 -> int-bit compare == float compare
            atomicMax(&redI[mbase + 0], __float_as_int(rm0));
            atomicMax(&redI[mbase + 1], __float_as_int(rm1));
            atomicMax(&redI[mbase + 2], __float_as_int(rm2));
            atomicMax(&redI[mbase + 3], __float_as_int(rm3));
        }
    }
    if (DO_ROWMAX) {
        __syncthreads();
        if (t < 128)       // d_out zeroed before launch; values >= 0 -> safe
            atomicMax((int*)&gfeat[(size_t)b * 1024 + m0 + t], redI[t]);
    }
}

extern "C" void kernel_launch(void* const* d_in, const int* in_sizes, int n_in,
                              void* d_out, int out_size, void* d_ws, size_t ws_size,
                              hipStream_t stream)
{
    const float* x   = (const float*)d_in[0];
    const float* sW0 = (const float*)d_in[1];
    const float* sb0 = (const float*)d_in[2];
    const float* sW1 = (const float*)d_in[3];
    const float* sb1 = (const float*)d_in[4];
    const float* sW2 = (const float*)d_in[5];
    const float* sb2 = (const float*)d_in[6];
    const float* gW0 = (const float*)d_in[7];
    const float* gb0 = (const float*)d_in[8];
    const float* gW1 = (const float*)d_in[9];
    const float* gb1 = (const float*)d_in[10];
    const float* mW0 = (const float*)d_in[11];
    const float* mb0 = (const float*)d_in[12];
    const float* mW1 = (const float*)d_in[13];
    const float* mb1 = (const float*)d_in[14];
    float* outp = (float*)d_out;

    char* ws = (char*)d_ws;
    int*            idx     = (int*)(ws);                        // 2 MB
    float4*         pts4    = (float4*)(ws + 2097152u);          // 256 KB
    unsigned short* Wb0     = (unsigned short*)(ws + 2359296u);  // 192 KB  gW0 bf16
    unsigned short* Wb1     = (unsigned short*)(ws + 2555904u);  // 512 KB  gW1 bf16
    unsigned short* Wb2     = (unsigned short*)(ws + 3080192u);  // 512 KB  mW0 bf16
    unsigned short* Wb3     = (unsigned short*)(ws + 3604480u);  // 64 KB   mW1 bf16
    unsigned short* F       = (unsigned short*)(ws + 4194304u);  // 12.6 MB [b][n][384] bf16
    unsigned short* point_t = (unsigned short*)(ws + 18874368u); // 12.6 MB [b][n][384] bf16
    unsigned short* gf0t    = (unsigned short*)(ws + 33554432u); // 8.4 MB  [b][n][256] bf16
    unsigned short* gft     = (unsigned short*)(ws + 50331648u); // 33.6 MB [b][n][1024] bf16
    unsigned short* msf0t   = (unsigned short*)(ws + 100663296u);// 8.4 MB  [b][n][256] bf16

    prep_all<<<dim3(2624), dim3(256), 0, stream>>>(
        x, pts4, gW0, gW1, mW0, mW1, Wb0, Wb1, Wb2, Wb3);
    knn_kernel10<<<dim3(16384), dim3(256), 0, stream>>>(pts4, idx);
    pointmlp_kernel<<<dim3(512, 3), dim3(256), 0, stream>>>(
        x, sW0, sb0, sW1, sb1, sW2, sb2, F);
    maxgather_bf16<<<dim3(16384), dim3(384), 0, stream>>>(F, idx, point_t);
    gemm_bf16<0, 0><<<dim3(2, 32, 4), dim3(256), 0, stream>>>(
        Wb0, point_t, gb0, gf0t, nullptr, 256, 384);
    gemm_bf16<0, 1><<<dim3(8, 32, 4), dim3(256), 0, stream>>>(
        Wb1, gf0t, gb1, gft, outp, 1024, 256);
    gemm_bf16<0, 0><<<dim3(2, 32, 4), dim3(256), 0, stream>>>(
        Wb2, gft, mb0, msf0t, nullptr, 256, 1024);
    gemm_bf16<1, 0><<<dim3(1, 32, 4), dim3(256), 0, stream>>>(
        Wb3, msf0t, mb1, outp + 4096, nullptr, 128, 256);
}

// Round 15
// 288.978 us; speedup vs baseline: 1.1698x; 1.0403x over previous
//
#include <hip/hip_runtime.h>
#include <hip/hip_bf16.h>

#define NPTS 4096
#define KNN  32

typedef __attribute__((ext_vector_type(8))) short short8;
typedef __attribute__((ext_vector_type(4))) float floatx4;
typedef unsigned short u16x2 __attribute__((ext_vector_type(2)));

__device__ __forceinline__ unsigned short f2bf(float f) {
    unsigned u = __float_as_uint(f);
    u = (u + 0x7FFFu + ((u >> 16) & 1u)) >> 16;
    return (unsigned short)u;
}

// ---------------- Kernel 0: pack points + convert weights to bf16 ------------
__global__ __launch_bounds__(256) void prep_all(
    const float* __restrict__ x, float4* __restrict__ pts4,
    const float* __restrict__ gW0, const float* __restrict__ gW1,
    const float* __restrict__ mW0, const float* __restrict__ mW1,
    unsigned short* __restrict__ Wb0, unsigned short* __restrict__ Wb1,
    unsigned short* __restrict__ Wb2, unsigned short* __restrict__ Wb3)
{
    const int blk = blockIdx.x, t = threadIdx.x;
    if (blk < 64) {
        const int i = blk * 256 + t;                 // 0..16383 = b*4096+n
        const int b = i >> 12, n = i & (NPTS - 1);
        const float* xb = x + (size_t)b * 3 * NPTS;
        const float qx = xb[n], qy = xb[NPTS + n], qz = xb[2 * NPTS + n];
        pts4[i] = make_float4(qx, qy, qz, qx * qx + qy * qy + qz * qz);
    } else {
        const int wi = (blk - 64) * 256 + t;         // 0..655359 (exact)
        float v; unsigned short* dst;
        if (wi < 98304)       { v = gW0[wi];          dst = Wb0 + wi; }
        else if (wi < 360448) { v = gW1[wi - 98304];  dst = Wb1 + (wi - 98304); }
        else if (wi < 622592) { v = mW0[wi - 360448]; dst = Wb2 + (wi - 360448); }
        else                  { v = mW1[wi - 622592]; dst = Wb3 + (wi - 622592); }
        *dst = f2bf(v);
    }
}

// ---------------- Kernel 1: exact KNN, block per query (R14, bound 320) ------
// Rolled fixed 8-iteration ballot+popcll search on the 9-bit key prefix
// (sign+exponent), 1 barrier/iter. Final octave bucket mean count ~95;
// collect bound raised 192 -> 320 (overflow prob ~0) + 2-entry rank pass.
__global__ __launch_bounds__(256) void knn_kernel11(const float4* __restrict__ pts4,
                                                    int* __restrict__ knn_out)
{
    __shared__ unsigned sred[2][4];
    __shared__ unsigned long long C[320];
    __shared__ unsigned ccnt;

    const int t = threadIdx.x, wid = t >> 6, lane = t & 63;
    const int q = blockIdx.x, b = q >> 12, n = q & (NPTS - 1);
    const float4* P = pts4 + ((size_t)b << 12);
    const float4 s = P[n];
    const float px = s.x, py = s.y, pz = s.z, sqn = s.w;

    if (t == 0) ccnt = 0u;

    unsigned key[16];
    #pragma unroll
    for (int g = 0; g < 4; ++g) {
        float4 c0 = P[((g * 4 + 0) << 8) + t];
        float4 c1 = P[((g * 4 + 1) << 8) + t];
        float4 c2 = P[((g * 4 + 2) << 8) + t];
        float4 c3 = P[((g * 4 + 3) << 8) + t];
        float d0 = (sqn + c0.w) - 2.0f * (px * c0.x + py * c0.y + pz * c0.z);
        float d1 = (sqn + c1.w) - 2.0f * (px * c1.x + py * c1.y + pz * c1.z);
        float d2 = (sqn + c2.w) - 2.0f * (px * c2.x + py * c2.y + pz * c2.z);
        float d3 = (sqn + c3.w) - 2.0f * (px * c3.x + py * c3.y + pz * c3.z);
        unsigned u0 = __float_as_uint(d0), u1 = __float_as_uint(d1);
        unsigned u2 = __float_as_uint(d2), u3 = __float_as_uint(d3);
        key[g * 4 + 0] = (u0 & 0x80000000u) ? ~u0 : (u0 | 0x80000000u);
        key[g * 4 + 1] = (u1 & 0x80000000u) ? ~u1 : (u1 | 0x80000000u);
        key[g * 4 + 2] = (u2 & 0x80000000u) ? ~u2 : (u2 | 0x80000000u);
        key[g * 4 + 3] = (u3 & 0x80000000u) ? ~u3 : (u3 | 0x80000000u);
    }

    unsigned lo = 0x100u, hi = 0x1FEu;
    for (int it = 0; it < 8; ++it) {
        const unsigned mid = (lo + hi) >> 1;
        const unsigned thr = (mid << 23) | 0x7FFFFFu;
        unsigned c = 0;
        #pragma unroll
        for (int r = 0; r < 16; ++r)
            c += (unsigned)__popcll(__ballot(key[r] <= thr));
        if (lane == 0) sred[it & 1][wid] = c;
        __syncthreads();
        const unsigned g = sred[it & 1][0] + sred[it & 1][1] +
                           sred[it & 1][2] + sred[it & 1][3];
        if (g >= 33u) hi = mid; else lo = mid + 1u;
    }
    const unsigned thrF = (lo << 23) | 0x7FFFFFu;

    #pragma unroll
    for (int r = 0; r < 16; ++r) {
        if (key[r] <= thrF) {
            unsigned p = atomicAdd(&ccnt, 1u);
            if (p < 320u)
                C[p] = ((unsigned long long)key[r] << 32) |
                       (unsigned)((r << 8) + t);
        }
    }
    __syncthreads();

    int nc = (int)ccnt; if (nc > 320) nc = 320;
    int* op = knn_out + (size_t)q * KNN;
    if (t < nc) {
        const unsigned long long me = C[t];
        int rank = 0;
        for (int j = 0; j < nc; ++j) rank += (C[j] < me) ? 1 : 0;
        if (rank >= 1 && rank <= KNN) op[rank - 1] = (int)(me & 0xFFFFFFFFu);
    }
    if (nc > 256 && t < nc - 256) {
        const unsigned long long me = C[256 + t];
        int rank = 0;
        for (int j = 0; j < nc; ++j) rank += (C[j] < me) ? 1 : 0;
        if (rank >= 1 && rank <= KNN) op[rank - 1] = (int)(me & 0xFFFFFFFFu);
    }
}

// ---------------- Kernel 2: per-point 3-layer MLP -> F bf16 [b][n][384] ------
__global__ __launch_bounds__(256) void pointmlp_kernel(
    const float* __restrict__ x,
    const float* __restrict__ sW0, const float* __restrict__ sb0,
    const float* __restrict__ sW1, const float* __restrict__ sb1,
    const float* __restrict__ sW2, const float* __restrict__ sb2,
    unsigned short* __restrict__ F)
{
    __shared__ __align__(16) float BUF[8192];
    __shared__ __align__(16) float h1s[64 * 36];
    __shared__ float b1s[64];
    __shared__ float b2s[128];
    __shared__ float pts[3 * 33];

    const int t = threadIdx.x;
    const int s = blockIdx.y;
    const int tile = blockIdx.x;
    const int b = tile >> 7;
    const int j0 = (tile & 127) << 5;
    const float* xb = x + (size_t)b * 3 * NPTS;

    if (t < 192) BUF[t] = sW0[s * 192 + t];
    else if (t < 256) BUF[t] = sb0[s * 64 + (t - 192)];
    if (t < 64) b1s[t] = sb1[s * 64 + t];
    if (t < 128) b2s[t] = sb2[s * 128 + t];
    if (t < 96) { int c = t >> 5, p = t & 31; pts[c * 33 + p] = xb[c * NPTS + j0 + p]; }
    {
        const float* W1 = sW1 + (size_t)s * 4096;
        int o = t & 63, q = t >> 6;
        #pragma unroll
        for (int r = 0; r < 4; ++r) {
            float4 w = *(const float4*)(W1 + o * 64 + q * 16 + r * 4);
            int i = q * 16 + r * 4;
            BUF[256 + (i + 0) * 64 + o] = w.x;
            BUF[256 + (i + 1) * 64 + o] = w.y;
            BUF[256 + (i + 2) * 64 + o] = w.z;
            BUF[256 + (i + 3) * 64 + o] = w.w;
        }
    }
    __syncthreads();
    const int o = t & 63, pg = t >> 6;
    float* h0 = BUF + 4352;
    {
        float w0 = BUF[o * 3], w1 = BUF[o * 3 + 1], w2 = BUF[o * 3 + 2], bb = BUF[192 + o];
        #pragma unroll
        for (int p = 0; p < 8; ++p) {
            int pp = pg * 8 + p;
            float a = bb + w0 * pts[pp] + w1 * pts[33 + pp] + w2 * pts[66 + pp];
            h0[o * 36 + pp] = fmaxf(a, 0.0f);
        }
    }
    __syncthreads();
    {
        float acc[8];
        #pragma unroll
        for (int p = 0; p < 8; ++p) acc[p] = b1s[o];
        for (int i = 0; i < 64; ++i) {
            float w = BUF[256 + i * 64 + o];
            float4 ha = *(const float4*)&h0[i * 36 + pg * 8];
            float4 hb = *(const float4*)&h0[i * 36 + pg * 8 + 4];
            acc[0] += w * ha.x; acc[1] += w * ha.y; acc[2] += w * ha.z; acc[3] += w * ha.w;
            acc[4] += w * hb.x; acc[5] += w * hb.y; acc[6] += w * hb.z; acc[7] += w * hb.w;
        }
        #pragma unroll
        for (int p = 0; p < 8; ++p) h1s[o * 36 + pg * 8 + p] = fmaxf(acc[p], 0.0f);
    }
    __syncthreads();
    {
        const float* W2 = sW2 + (size_t)s * 8192;
        int o2 = t & 127, q = t >> 7;
        #pragma unroll
        for (int r = 0; r < 8; ++r) {
            float4 w = *(const float4*)(W2 + o2 * 64 + q * 32 + r * 4);
            int i = q * 32 + r * 4;
            BUF[(i + 0) * 128 + o2] = w.x;
            BUF[(i + 1) * 128 + o2] = w.y;
            BUF[(i + 2) * 128 + o2] = w.z;
            BUF[(i + 3) * 128 + o2] = w.w;
        }
    }
    __syncthreads();
    {
        int o2 = t & 127, ph = t >> 7;
        float acc[16];
        #pragma unroll
        for (int p = 0; p < 16; ++p) acc[p] = b2s[o2];
        for (int i = 0; i < 64; ++i) {
            float w = BUF[i * 128 + o2];
            float4 ha = *(const float4*)&h1s[i * 36 + ph * 16];
            float4 hb = *(const float4*)&h1s[i * 36 + ph * 16 + 4];
            float4 hc = *(const float4*)&h1s[i * 36 + ph * 16 + 8];
            float4 hd = *(const float4*)&h1s[i * 36 + ph * 16 + 12];
            acc[0]  += w * ha.x; acc[1]  += w * ha.y; acc[2]  += w * ha.z; acc[3]  += w * ha.w;
            acc[4]  += w * hb.x; acc[5]  += w * hb.y; acc[6]  += w * hb.z; acc[7]  += w * hb.w;
            acc[8]  += w * hc.x; acc[9]  += w * hc.y; acc[10] += w * hc.z; acc[11] += w * hc.w;
            acc[12] += w * hd.x; acc[13] += w * hd.y; acc[14] += w * hd.z; acc[15] += w * hd.w;
        }
        #pragma unroll
        for (int p = 0; p < 16; ++p) {
            int j = j0 + ph * 16 + p;
            F[((size_t)b * NPTS + j) * 384 + s * 128 + o2] = f2bf(fmaxf(acc[p], 0.0f));
        }
    }
}

// ---------------- Kernel 3: gather-max, 2 channels/lane (pk_max_u16) ---------
// uint16 compare valid: post-relu bf16 (>=0) bit patterns are value-monotone.
__global__ __launch_bounds__(192) void maxgather_bf16(
    const unsigned short* __restrict__ F, const int* __restrict__ knn,
    unsigned short* __restrict__ pt)
{
    __shared__ int idxS[KNN];
    const int q = blockIdx.x;            // b*4096 + n
    const int b = q >> 12;
    const int t = threadIdx.x;           // channel-pair 0..191
    if (t < KNN) idxS[t] = knn[(size_t)q * KNN + t];
    __syncthreads();
    const unsigned short* Fb = F + (size_t)b * NPTS * 384 + t * 2;
    u16x2 m = (u16x2)0;
    #pragma unroll 8
    for (int k = 0; k < KNN; ++k) {
        u16x2 v = *(const u16x2*)(Fb + (size_t)idxS[k] * 384);
        m = __builtin_elementwise_max(m, v);
    }
    *(u16x2*)(pt + (size_t)q * 384 + t * 2) = m;
}

// ---------------- Kernel 4: bf16 MFMA GEMM + bias + relu (R10-passing) -------
template<int DO_ROWMAX>
__global__ __launch_bounds__(256) void gemm_bf16(
    const unsigned short* __restrict__ Wb, const unsigned short* __restrict__ Bt,
    const float* __restrict__ bias, void* __restrict__ outp,
    float* __restrict__ gfeat, int M, int K)
{
    __shared__ __align__(16) unsigned short As[128 * 40]; // [m][k] pad 40
    __shared__ __align__(16) unsigned short Bs[128 * 40]; // [n][k] pad 40
    __shared__ float biasS[128];
    __shared__ int redI[128];

    const int t = threadIdx.x;
    const int b = blockIdx.z;
    const int m0 = blockIdx.x * 128;
    const int n0 = blockIdx.y * 128;
    if (t < 128) biasS[t] = bias[m0 + t];
    if (DO_ROWMAX && t < 128) redI[t] = 0;

    const int wave = t >> 6, lane = t & 63, quad = lane >> 4, l15 = lane & 15;
    const int wr = wave >> 1, wc = wave & 1;

    const int am = t & 127, akh = t >> 7;
    const unsigned short* Wp = Wb + (size_t)(m0 + am) * K + akh * 16;
    const int bn = t >> 2, bq = t & 3;
    const unsigned short* Bp = Bt + ((size_t)b * NPTS + n0) * K;

    floatx4 acc[16];
    #pragma unroll
    for (int i = 0; i < 16; ++i) acc[i] = (floatx4){0.f, 0.f, 0.f, 0.f};

    const int nk = K >> 5;
    for (int kt = 0; kt < nk; ++kt) {
        const int k0 = kt << 5;
        uint4 av0 = *(const uint4*)(Wp + k0);
        uint4 av1 = *(const uint4*)(Wp + k0 + 8);
        uint4 bv0 = *(const uint4*)(Bp + (size_t)bn * K + k0 + bq * 8);
        uint4 bv1 = *(const uint4*)(Bp + (size_t)(bn + 64) * K + k0 + bq * 8);
        __syncthreads();
        {
            uint4* dst = (uint4*)&As[am * 40 + akh * 16];
            dst[0] = av0;
            dst[1] = av1;
            *(uint4*)&Bs[bn * 40 + bq * 8] = bv0;
            *(uint4*)&Bs[(bn + 64) * 40 + bq * 8] = bv1;
        }
        __syncthreads();
        short8 af[4], bfv[4];
        #pragma unroll
        for (int i = 0; i < 4; ++i)
            af[i] = *(const short8*)&As[(wr * 64 + i * 16 + l15) * 40 + quad * 8];
        #pragma unroll
        for (int j = 0; j < 4; ++j)
            bfv[j] = *(const short8*)&Bs[(wc * 64 + j * 16 + l15) * 40 + quad * 8];
        #pragma unroll
        for (int i = 0; i < 4; ++i)
            #pragma unroll
            for (int j = 0; j < 4; ++j)
                acc[i * 4 + j] = __builtin_amdgcn_mfma_f32_16x16x32_bf16(
                    af[i], bfv[j], acc[i * 4 + j], 0, 0, 0);
    }

    #pragma unroll
    for (int i = 0; i < 4; ++i) {
        const int mbase = wr * 64 + i * 16 + quad * 4;
        float rm0 = 0.f, rm1 = 0.f, rm2 = 0.f, rm3 = 0.f;
        #pragma unroll
        for (int j = 0; j < 4; ++j) {
            const int n = n0 + wc * 64 + j * 16 + l15;
            float v0 = fmaxf(acc[i * 4 + j][0] + biasS[mbase + 0], 0.f);
            float v1 = fmaxf(acc[i * 4 + j][1] + biasS[mbase + 1], 0.f);
            float v2 = fmaxf(acc[i * 4 + j][2] + biasS[mbase + 2], 0.f);
            float v3 = fmaxf(acc[i * 4 + j][3] + biasS[mbase + 3], 0.f);
            if (DO_ROWMAX) {
                rm0 = fmaxf(rm0, v0); rm1 = fmaxf(rm1, v1);
                rm2 = fmaxf(rm2, v2); rm3 = fmaxf(rm3, v3);
            }
            ushort4 pk;
            pk.x = f2bf(v0); pk.y = f2bf(v1); pk.z = f2bf(v2); pk.w = f2bf(v3);
            *(ushort4*)((unsigned short*)outp +
                        ((size_t)b * NPTS + n) * M + m0 + mbase) = pk;
        }
        if (DO_ROWMAX) {
            atomicMax(&redI[mbase + 0], __float_as_int(rm0));
            atomicMax(&redI[mbase + 1], __float_as_int(rm1));
            atomicMax(&redI[mbase + 2], __float_as_int(rm2));
            atomicMax(&redI[mbase + 3], __float_as_int(rm3));
        }
    }
    if (DO_ROWMAX) {
        __syncthreads();
        if (t < 128)       // d_out zeroed before launch; values >= 0 -> safe
            atomicMax((int*)&gfeat[(size_t)b * 1024 + m0 + t], redI[t]);
    }
}

// ---------------- Kernel 5: fused head = gemm3 + gemm4 -----------------------
// Phase1: H[64n][256m] = relu(mW0[256x1024] * gft_tile + mb0) (bf16, in LDS)
// Phase2: out fp32 [b][128][4096] = relu(mW1[128x256] * H + mb1)
// Same k-order and f2bf points as the unfused pair -> bit-identical numerics.
__global__ __launch_bounds__(256) void fused_head(
    const unsigned short* __restrict__ Wb2, const unsigned short* __restrict__ Wb3,
    const float* __restrict__ mb0, const float* __restrict__ mb1,
    const unsigned short* __restrict__ gft, float* __restrict__ outp)
{
    __shared__ __align__(16) unsigned short As[256 * 40];
    __shared__ __align__(16) unsigned short Bs[64 * 40];
    __shared__ __align__(16) unsigned short H[64 * 264];
    __shared__ float b0s[256];
    __shared__ float b1s[128];

    const int t = threadIdx.x;
    const int n0 = blockIdx.x * 64;
    const int b = blockIdx.y;
    b0s[t] = mb0[t];
    if (t < 128) b1s[t] = mb1[t];

    const int wave = t >> 6, lane = t & 63, quad = lane >> 4, l15 = lane & 15;

    // ---- phase 1: C1[256m x 64n], K = 1024 ----
    const unsigned short* Ap = Wb2 + (size_t)t * 1024;      // A row t (m = t)
    const int bn = t >> 2, bq = t & 3;
    const unsigned short* Bp = gft + ((size_t)b * NPTS + n0) * 1024;

    floatx4 acc[16];
    #pragma unroll
    for (int i = 0; i < 16; ++i) acc[i] = (floatx4){0.f, 0.f, 0.f, 0.f};

    for (int kt = 0; kt < 32; ++kt) {
        const int k0 = kt << 5;
        uint4 a0 = *(const uint4*)(Ap + k0);
        uint4 a1 = *(const uint4*)(Ap + k0 + 8);
        uint4 a2 = *(const uint4*)(Ap + k0 + 16);
        uint4 a3 = *(const uint4*)(Ap + k0 + 24);
        uint4 bv = *(const uint4*)(Bp + (size_t)bn * 1024 + k0 + bq * 8);
        __syncthreads();
        *(uint4*)&As[t * 40 + 0]  = a0;
        *(uint4*)&As[t * 40 + 8]  = a1;
        *(uint4*)&As[t * 40 + 16] = a2;
        *(uint4*)&As[t * 40 + 24] = a3;
        *(uint4*)&Bs[bn * 40 + bq * 8] = bv;
        __syncthreads();
        short8 af[4], bfv[4];
        #pragma unroll
        for (int i = 0; i < 4; ++i)
            af[i] = *(const short8*)&As[(wave * 64 + i * 16 + l15) * 40 + quad * 8];
        #pragma unroll
        for (int j = 0; j < 4; ++j)
            bfv[j] = *(const short8*)&Bs[(j * 16 + l15) * 40 + quad * 8];
        #pragma unroll
        for (int i = 0; i < 4; ++i)
            #pragma unroll
            for (int j = 0; j < 4; ++j)
                acc[i * 4 + j] = __builtin_amdgcn_mfma_f32_16x16x32_bf16(
                    af[i], bfv[j], acc[i * 4 + j], 0, 0, 0);
    }
    // epilogue -> H[n][m] bf16
    #pragma unroll
    for (int i = 0; i < 4; ++i) {
        const int mbase = wave * 64 + i * 16 + quad * 4;
        #pragma unroll
        for (int j = 0; j < 4; ++j) {
            const int nl = j * 16 + l15;
            ushort4 pk;
            pk.x = f2bf(fmaxf(acc[i * 4 + j][0] + b0s[mbase + 0], 0.f));
            pk.y = f2bf(fmaxf(acc[i * 4 + j][1] + b0s[mbase + 1], 0.f));
            pk.z = f2bf(fmaxf(acc[i * 4 + j][2] + b0s[mbase + 2], 0.f));
            pk.w = f2bf(fmaxf(acc[i * 4 + j][3] + b0s[mbase + 3], 0.f));
            *(ushort4*)&H[nl * 264 + mbase] = pk;
        }
    }

    // ---- phase 2: C2[128m x 64n], K = 256 (B = H in LDS) ----
    floatx4 acc2[8];
    #pragma unroll
    for (int i = 0; i < 8; ++i) acc2[i] = (floatx4){0.f, 0.f, 0.f, 0.f};
    const int am2 = t & 127, ah = t >> 7;

    for (int kt = 0; kt < 8; ++kt) {
        const int k0 = kt << 5;
        uint4 a0 = *(const uint4*)(Wb3 + (size_t)am2 * 256 + k0 + ah * 16);
        uint4 a1 = *(const uint4*)(Wb3 + (size_t)am2 * 256 + k0 + ah * 16 + 8);
        __syncthreads();   // protects As reuse; first iter: H visibility
        *(uint4*)&As[am2 * 40 + ah * 16]     = a0;
        *(uint4*)&As[am2 * 40 + ah * 16 + 8] = a1;
        __syncthreads();
        short8 af2[2], bf2[4];
        #pragma unroll
        for (int i = 0; i < 2; ++i)
            af2[i] = *(const short8*)&As[(wave * 32 + i * 16 + l15) * 40 + quad * 8];
        #pragma unroll
        for (int j = 0; j < 4; ++j)
            bf2[j] = *(const short8*)&H[(j * 16 + l15) * 264 + k0 + quad * 8];
        #pragma unroll
        for (int i = 0; i < 2; ++i)
            #pragma unroll
            for (int j = 0; j < 4; ++j)
                acc2[i * 4 + j] = __builtin_amdgcn_mfma_f32_16x16x32_bf16(
                    af2[i], bf2[j], acc2[i * 4 + j], 0, 0, 0);
    }
    #pragma unroll
    for (int i = 0; i < 2; ++i) {
        const int m2 = wave * 32 + i * 16 + quad * 4;
        #pragma unroll
        for (int j = 0; j < 4; ++j) {
            const int n = n0 + j * 16 + l15;
            float* o = outp + ((size_t)b * 128 + m2) * NPTS + n;
            o[0 * NPTS] = fmaxf(acc2[i * 4 + j][0] + b1s[m2 + 0], 0.f);
            o[1 * NPTS] = fmaxf(acc2[i * 4 + j][1] + b1s[m2 + 1], 0.f);
            o[2 * NPTS] = fmaxf(acc2[i * 4 + j][2] + b1s[m2 + 2], 0.f);
            o[3 * NPTS] = fmaxf(acc2[i * 4 + j][3] + b1s[m2 + 3], 0.f);
        }
    }
}

extern "C" void kernel_launch(void* const* d_in, const int* in_sizes, int n_in,
                              void* d_out, int out_size, void* d_ws, size_t ws_size,
                              hipStream_t stream)
{
    const float* x   = (const float*)d_in[0];
    const float* sW0 = (const float*)d_in[1];
    const float* sb0 = (const float*)d_in[2];
    const float* sW1 = (const float*)d_in[3];
    const float* sb1 = (const float*)d_in[4];
    const float* sW2 = (const float*)d_in[5];
    const float* sb2 = (const float*)d_in[6];
    const float* gW0 = (const float*)d_in[7];
    const float* gb0 = (const float*)d_in[8];
    const float* gW1 = (const float*)d_in[9];
    const float* gb1 = (const float*)d_in[10];
    const float* mW0 = (const float*)d_in[11];
    const float* mb0 = (const float*)d_in[12];
    const float* mW1 = (const float*)d_in[13];
    const float* mb1 = (const float*)d_in[14];
    float* outp = (float*)d_out;

    char* ws = (char*)d_ws;
    int*            idx     = (int*)(ws);                        // 2 MB
    float4*         pts4    = (float4*)(ws + 2097152u);          // 256 KB
    unsigned short* Wb0     = (unsigned short*)(ws + 2359296u);  // 192 KB  gW0 bf16
    unsigned short* Wb1     = (unsigned short*)(ws + 2555904u);  // 512 KB  gW1 bf16
    unsigned short* Wb2     = (unsigned short*)(ws + 3080192u);  // 512 KB  mW0 bf16
    unsigned short* Wb3     = (unsigned short*)(ws + 3604480u);  // 64 KB   mW1 bf16
    unsigned short* F       = (unsigned short*)(ws + 4194304u);  // 12.6 MB [b][n][384] bf16
    unsigned short* point_t = (unsigned short*)(ws + 18874368u); // 12.6 MB [b][n][384] bf16
    unsigned short* gf0t    = (unsigned short*)(ws + 33554432u); // 8.4 MB  [b][n][256] bf16
    unsigned short* gft     = (unsigned short*)(ws + 50331648u); // 33.6 MB [b][n][1024] bf16

    prep_all<<<dim3(2624), dim3(256), 0, stream>>>(
        x, pts4, gW0, gW1, mW0, mW1, Wb0, Wb1, Wb2, Wb3);
    knn_kernel11<<<dim3(16384), dim3(256), 0, stream>>>(pts4, idx);
    pointmlp_kernel<<<dim3(512, 3), dim3(256), 0, stream>>>(
        x, sW0, sb0, sW1, sb1, sW2, sb2, F);
    maxgather_bf16<<<dim3(16384), dim3(192), 0, stream>>>(F, idx, point_t);
    gemm_bf16<0><<<dim3(2, 32, 4), dim3(256), 0, stream>>>(
        Wb0, point_t, gb0, gf0t, nullptr, 256, 384);
    gemm_bf16<1><<<dim3(8, 32, 4), dim3(256), 0, stream>>>(
        Wb1, gf0t, gb1, gft, outp, 1024, 256);
    fused_head<<<dim3(64, 4), dim3(256), 0, stream>>>(
        Wb2, Wb3, mb0, mb1, gft, outp + 4096);
}

// Round 16
// 286.762 us; speedup vs baseline: 1.1788x; 1.0077x over previous
//
#include <hip/hip_runtime.h>
#include <hip/hip_bf16.h>

#define NPTS 4096
#define KNN  32

typedef __attribute__((ext_vector_type(8))) short short8;
typedef __attribute__((ext_vector_type(4))) float floatx4;
typedef unsigned short u16x2 __attribute__((ext_vector_type(2)));

__device__ __forceinline__ unsigned short f2bf(float f) {
    unsigned u = __float_as_uint(f);
    u = (u + 0x7FFFu + ((u >> 16) & 1u)) >> 16;
    return (unsigned short)u;
}

// ---------------- Kernel 0: pack points + convert weights to bf16 ------------
__global__ __launch_bounds__(256) void prep_all(
    const float* __restrict__ x, float4* __restrict__ pts4,
    const float* __restrict__ gW0, const float* __restrict__ gW1,
    const float* __restrict__ mW0, const float* __restrict__ mW1,
    unsigned short* __restrict__ Wb0, unsigned short* __restrict__ Wb1,
    unsigned short* __restrict__ Wb2, unsigned short* __restrict__ Wb3)
{
    const int blk = blockIdx.x, t = threadIdx.x;
    if (blk < 64) {
        const int i = blk * 256 + t;                 // 0..16383 = b*4096+n
        const int b = i >> 12, n = i & (NPTS - 1);
        const float* xb = x + (size_t)b * 3 * NPTS;
        const float qx = xb[n], qy = xb[NPTS + n], qz = xb[2 * NPTS + n];
        pts4[i] = make_float4(qx, qy, qz, qx * qx + qy * qy + qz * qz);
    } else {
        const int wi = (blk - 64) * 256 + t;         // 0..655359 (exact)
        float v; unsigned short* dst;
        if (wi < 98304)       { v = gW0[wi];          dst = Wb0 + wi; }
        else if (wi < 360448) { v = gW1[wi - 98304];  dst = Wb1 + (wi - 98304); }
        else if (wi < 622592) { v = mW0[wi - 360448]; dst = Wb2 + (wi - 360448); }
        else                  { v = mW1[wi - 622592]; dst = Wb3 + (wi - 622592); }
        *dst = f2bf(v);
    }
}

// ---------------- Kernel 1: exact KNN, block per query -----------------------
// 8 fixed prefix iterations (9-bit sign+exponent) + one count pass at the
// octave top + RARE dynamic mantissa refinement while count > 256 (outlier
// queries: Gaussian-tail density gradient makes the octave count exceed any
// fixed bound -- R14/R15's residual absmax drift). Exit invariant:
// 33 <= count(thrF) <= 256 -> collect NEVER overflows -> exact deterministic
// top-33 by (key, idx); ranks 1..32 emitted (rank 0 = self dropped).
__global__ __launch_bounds__(256) void knn_kernel12(const float4* __restrict__ pts4,
                                                    int* __restrict__ knn_out)
{
    __shared__ unsigned sred[2][4];
    __shared__ unsigned long long C[256];
    __shared__ unsigned ccnt;

    const int t = threadIdx.x, wid = t >> 6, lane = t & 63;
    const int q = blockIdx.x, b = q >> 12, n = q & (NPTS - 1);
    const float4* P = pts4 + ((size_t)b << 12);
    const float4 s = P[n];
    const float px = s.x, py = s.y, pz = s.z, sqn = s.w;

    if (t == 0) ccnt = 0u;

    unsigned key[16];
    #pragma unroll
    for (int g = 0; g < 4; ++g) {
        float4 c0 = P[((g * 4 + 0) << 8) + t];
        float4 c1 = P[((g * 4 + 1) << 8) + t];
        float4 c2 = P[((g * 4 + 2) << 8) + t];
        float4 c3 = P[((g * 4 + 3) << 8) + t];
        float d0 = (sqn + c0.w) - 2.0f * (px * c0.x + py * c0.y + pz * c0.z);
        float d1 = (sqn + c1.w) - 2.0f * (px * c1.x + py * c1.y + pz * c1.z);
        float d2 = (sqn + c2.w) - 2.0f * (px * c2.x + py * c2.y + pz * c2.z);
        float d3 = (sqn + c3.w) - 2.0f * (px * c3.x + py * c3.y + pz * c3.z);
        unsigned u0 = __float_as_uint(d0), u1 = __float_as_uint(d1);
        unsigned u2 = __float_as_uint(d2), u3 = __float_as_uint(d3);
        key[g * 4 + 0] = (u0 & 0x80000000u) ? ~u0 : (u0 | 0x80000000u);
        key[g * 4 + 1] = (u1 & 0x80000000u) ? ~u1 : (u1 | 0x80000000u);
        key[g * 4 + 2] = (u2 & 0x80000000u) ? ~u2 : (u2 | 0x80000000u);
        key[g * 4 + 3] = (u3 & 0x80000000u) ? ~u3 : (u3 | 0x80000000u);
    }

    int pp = 0;   // count-pass parity (2-slot sred scheme, 1 barrier/pass)
    auto countLE = [&](unsigned thr) -> unsigned {
        unsigned c = 0;
        #pragma unroll
        for (int r = 0; r < 16; ++r)
            c += (unsigned)__popcll(__ballot(key[r] <= thr));
        if (lane == 0) sred[pp & 1][wid] = c;
        __syncthreads();
        const unsigned g = sred[pp & 1][0] + sred[pp & 1][1] +
                           sred[pp & 1][2] + sred[pp & 1][3];
        ++pp;
        return g;
    };

    // fixed 8-iteration search on 9-bit prefix
    unsigned lo = 0x100u, hi = 0x1FEu;
    for (int it = 0; it < 8; ++it) {
        const unsigned mid = (lo + hi) >> 1;
        const unsigned g = countLE((mid << 23) | 0x7FFFFFu);
        if (g >= 33u) hi = mid; else lo = mid + 1u;
    }
    // refinement: shrink threshold until candidate count <= 256 (rare)
    unsigned loK = lo << 23;
    unsigned hiK = (lo << 23) | 0x7FFFFFu;
    unsigned cntF = countLE(hiK);             // >= 33 by search invariant
    while (cntF > 256u && loK < hiK) {        // uniform condition; terminates
        const unsigned midK = loK + ((hiK - loK) >> 1);
        const unsigned c = countLE(midK);
        if (c >= 33u) { hiK = midK; cntF = c; } else loK = midK + 1u;
    }
    const unsigned thrF = hiK;

    #pragma unroll
    for (int r = 0; r < 16; ++r) {
        if (key[r] <= thrF) {
            unsigned p = atomicAdd(&ccnt, 1u);
            if (p < 256u)
                C[p] = ((unsigned long long)key[r] << 32) |
                       (unsigned)((r << 8) + t);
        }
    }
    __syncthreads();

    int nc = (int)ccnt; if (nc > 256) nc = 256;   // cntF <= 256 guaranteed
    if (t < nc) {
        const unsigned long long me = C[t];
        int rank = 0;
        for (int j = 0; j < nc; ++j) rank += (C[j] < me) ? 1 : 0;
        if (rank >= 1 && rank <= KNN)
            knn_out[(size_t)q * KNN + (rank - 1)] = (int)(me & 0xFFFFFFFFu);
    }
}

// ---------------- Kernel 2: per-point 3-layer MLP -> F bf16 [b][n][384] ------
__global__ __launch_bounds__(256) void pointmlp_kernel(
    const float* __restrict__ x,
    const float* __restrict__ sW0, const float* __restrict__ sb0,
    const float* __restrict__ sW1, const float* __restrict__ sb1,
    const float* __restrict__ sW2, const float* __restrict__ sb2,
    unsigned short* __restrict__ F)
{
    __shared__ __align__(16) float BUF[8192];
    __shared__ __align__(16) float h1s[64 * 36];
    __shared__ float b1s[64];
    __shared__ float b2s[128];
    __shared__ float pts[3 * 33];

    const int t = threadIdx.x;
    const int s = blockIdx.y;
    const int tile = blockIdx.x;
    const int b = tile >> 7;
    const int j0 = (tile & 127) << 5;
    const float* xb = x + (size_t)b * 3 * NPTS;

    if (t < 192) BUF[t] = sW0[s * 192 + t];
    else if (t < 256) BUF[t] = sb0[s * 64 + (t - 192)];
    if (t < 64) b1s[t] = sb1[s * 64 + t];
    if (t < 128) b2s[t] = sb2[s * 128 + t];
    if (t < 96) { int c = t >> 5, p = t & 31; pts[c * 33 + p] = xb[c * NPTS + j0 + p]; }
    {
        const float* W1 = sW1 + (size_t)s * 4096;
        int o = t & 63, q = t >> 6;
        #pragma unroll
        for (int r = 0; r < 4; ++r) {
            float4 w = *(const float4*)(W1 + o * 64 + q * 16 + r * 4);
            int i = q * 16 + r * 4;
            BUF[256 + (i + 0) * 64 + o] = w.x;
            BUF[256 + (i + 1) * 64 + o] = w.y;
            BUF[256 + (i + 2) * 64 + o] = w.z;
            BUF[256 + (i + 3) * 64 + o] = w.w;
        }
    }
    __syncthreads();
    const int o = t & 63, pg = t >> 6;
    float* h0 = BUF + 4352;
    {
        float w0 = BUF[o * 3], w1 = BUF[o * 3 + 1], w2 = BUF[o * 3 + 2], bb = BUF[192 + o];
        #pragma unroll
        for (int p = 0; p < 8; ++p) {
            int pp = pg * 8 + p;
            float a = bb + w0 * pts[pp] + w1 * pts[33 + pp] + w2 * pts[66 + pp];
            h0[o * 36 + pp] = fmaxf(a, 0.0f);
        }
    }
    __syncthreads();
    {
        float acc[8];
        #pragma unroll
        for (int p = 0; p < 8; ++p) acc[p] = b1s[o];
        for (int i = 0; i < 64; ++i) {
            float w = BUF[256 + i * 64 + o];
            float4 ha = *(const float4*)&h0[i * 36 + pg * 8];
            float4 hb = *(const float4*)&h0[i * 36 + pg * 8 + 4];
            acc[0] += w * ha.x; acc[1] += w * ha.y; acc[2] += w * ha.z; acc[3] += w * ha.w;
            acc[4] += w * hb.x; acc[5] += w * hb.y; acc[6] += w * hb.z; acc[7] += w * hb.w;
        }
        #pragma unroll
        for (int p = 0; p < 8; ++p) h1s[o * 36 + pg * 8 + p] = fmaxf(acc[p], 0.0f);
    }
    __syncthreads();
    {
        const float* W2 = sW2 + (size_t)s * 8192;
        int o2 = t & 127, q = t >> 7;
        #pragma unroll
        for (int r = 0; r < 8; ++r) {
            float4 w = *(const float4*)(W2 + o2 * 64 + q * 32 + r * 4);
            int i = q * 32 + r * 4;
            BUF[(i + 0) * 128 + o2] = w.x;
            BUF[(i + 1) * 128 + o2] = w.y;
            BUF[(i + 2) * 128 + o2] = w.z;
            BUF[(i + 3) * 128 + o2] = w.w;
        }
    }
    __syncthreads();
    {
        int o2 = t & 127, ph = t >> 7;
        float acc[16];
        #pragma unroll
        for (int p = 0; p < 16; ++p) acc[p] = b2s[o2];
        for (int i = 0; i < 64; ++i) {
            float w = BUF[i * 128 + o2];
            float4 ha = *(const float4*)&h1s[i * 36 + ph * 16];
            float4 hb = *(const float4*)&h1s[i * 36 + ph * 16 + 4];
            float4 hc = *(const float4*)&h1s[i * 36 + ph * 16 + 8];
            float4 hd = *(const float4*)&h1s[i * 36 + ph * 16 + 12];
            acc[0]  += w * ha.x; acc[1]  += w * ha.y; acc[2]  += w * ha.z; acc[3]  += w * ha.w;
            acc[4]  += w * hb.x; acc[5]  += w * hb.y; acc[6]  += w * hb.z; acc[7]  += w * hb.w;
            acc[8]  += w * hc.x; acc[9]  += w * hc.y; acc[10] += w * hc.z; acc[11] += w * hc.w;
            acc[12] += w * hd.x; acc[13] += w * hd.y; acc[14] += w * hd.z; acc[15] += w * hd.w;
        }
        #pragma unroll
        for (int p = 0; p < 16; ++p) {
            int j = j0 + ph * 16 + p;
            F[((size_t)b * NPTS + j) * 384 + s * 128 + o2] = f2bf(fmaxf(acc[p], 0.0f));
        }
    }
}

// ---------------- Kernel 3: gather-max, 2 channels/lane (pk_max_u16) ---------
__global__ __launch_bounds__(192) void maxgather_bf16(
    const unsigned short* __restrict__ F, const int* __restrict__ knn,
    unsigned short* __restrict__ pt)
{
    __shared__ int idxS[KNN];
    const int q = blockIdx.x;            // b*4096 + n
    const int b = q >> 12;
    const int t = threadIdx.x;           // channel-pair 0..191
    if (t < KNN) idxS[t] = knn[(size_t)q * KNN + t];
    __syncthreads();
    const unsigned short* Fb = F + (size_t)b * NPTS * 384 + t * 2;
    u16x2 m = (u16x2)0;
    #pragma unroll 8
    for (int k = 0; k < KNN; ++k) {
        u16x2 v = *(const u16x2*)(Fb + (size_t)idxS[k] * 384);
        m = __builtin_elementwise_max(m, v);
    }
    *(u16x2*)(pt + (size_t)q * 384 + t * 2) = m;
}

// ---------------- Kernel 4: bf16 MFMA GEMM + bias + relu (R10-passing) -------
template<int DO_ROWMAX>
__global__ __launch_bounds__(256) void gemm_bf16(
    const unsigned short* __restrict__ Wb, const unsigned short* __restrict__ Bt,
    const float* __restrict__ bias, void* __restrict__ outp,
    float* __restrict__ gfeat, int M, int K)
{
    __shared__ __align__(16) unsigned short As[128 * 40]; // [m][k] pad 40
    __shared__ __align__(16) unsigned short Bs[128 * 40]; // [n][k] pad 40
    __shared__ float biasS[128];
    __shared__ int redI[128];

    const int t = threadIdx.x;
    const int b = blockIdx.z;
    const int m0 = blockIdx.x * 128;
    const int n0 = blockIdx.y * 128;
    if (t < 128) biasS[t] = bias[m0 + t];
    if (DO_ROWMAX && t < 128) redI[t] = 0;

    const int wave = t >> 6, lane = t & 63, quad = lane >> 4, l15 = lane & 15;
    const int wr = wave >> 1, wc = wave & 1;

    const int am = t & 127, akh = t >> 7;
    const unsigned short* Wp = Wb + (size_t)(m0 + am) * K + akh * 16;
    const int bn = t >> 2, bq = t & 3;
    const unsigned short* Bp = Bt + ((size_t)b * NPTS + n0) * K;

    floatx4 acc[16];
    #pragma unroll
    for (int i = 0; i < 16; ++i) acc[i] = (floatx4){0.f, 0.f, 0.f, 0.f};

    const int nk = K >> 5;
    for (int kt = 0; kt < nk; ++kt) {
        const int k0 = kt << 5;
        uint4 av0 = *(const uint4*)(Wp + k0);
        uint4 av1 = *(const uint4*)(Wp + k0 + 8);
        uint4 bv0 = *(const uint4*)(Bp + (size_t)bn * K + k0 + bq * 8);
        uint4 bv1 = *(const uint4*)(Bp + (size_t)(bn + 64) * K + k0 + bq * 8);
        __syncthreads();
        {
            uint4* dst = (uint4*)&As[am * 40 + akh * 16];
            dst[0] = av0;
            dst[1] = av1;
            *(uint4*)&Bs[bn * 40 + bq * 8] = bv0;
            *(uint4*)&Bs[(bn + 64) * 40 + bq * 8] = bv1;
        }
        __syncthreads();
        short8 af[4], bfv[4];
        #pragma unroll
        for (int i = 0; i < 4; ++i)
            af[i] = *(const short8*)&As[(wr * 64 + i * 16 + l15) * 40 + quad * 8];
        #pragma unroll
        for (int j = 0; j < 4; ++j)
            bfv[j] = *(const short8*)&Bs[(wc * 64 + j * 16 + l15) * 40 + quad * 8];
        #pragma unroll
        for (int i = 0; i < 4; ++i)
            #pragma unroll
            for (int j = 0; j < 4; ++j)
                acc[i * 4 + j] = __builtin_amdgcn_mfma_f32_16x16x32_bf16(
                    af[i], bfv[j], acc[i * 4 + j], 0, 0, 0);
    }

    #pragma unroll
    for (int i = 0; i < 4; ++i) {
        const int mbase = wr * 64 + i * 16 + quad * 4;
        float rm0 = 0.f, rm1 = 0.f, rm2 = 0.f, rm3 = 0.f;
        #pragma unroll
        for (int j = 0; j < 4; ++j) {
            const int n = n0 + wc * 64 + j * 16 + l15;
            float v0 = fmaxf(acc[i * 4 + j][0] + biasS[mbase + 0], 0.f);
            float v1 = fmaxf(acc[i * 4 + j][1] + biasS[mbase + 1], 0.f);
            float v2 = fmaxf(acc[i * 4 + j][2] + biasS[mbase + 2], 0.f);
            float v3 = fmaxf(acc[i * 4 + j][3] + biasS[mbase + 3], 0.f);
            if (DO_ROWMAX) {
                rm0 = fmaxf(rm0, v0); rm1 = fmaxf(rm1, v1);
                rm2 = fmaxf(rm2, v2); rm3 = fmaxf(rm3, v3);
            }
            ushort4 pk;
            pk.x = f2bf(v0); pk.y = f2bf(v1); pk.z = f2bf(v2); pk.w = f2bf(v3);
            *(ushort4*)((unsigned short*)outp +
                        ((size_t)b * NPTS + n) * M + m0 + mbase) = pk;
        }
        if (DO_ROWMAX) {
            atomicMax(&redI[mbase + 0], __float_as_int(rm0));
            atomicMax(&redI[mbase + 1], __float_as_int(rm1));
            atomicMax(&redI[mbase + 2], __float_as_int(rm2));
            atomicMax(&redI[mbase + 3], __float_as_int(rm3));
        }
    }
    if (DO_ROWMAX) {
        __syncthreads();
        if (t < 128)       // d_out zeroed before launch; values >= 0 -> safe
            atomicMax((int*)&gfeat[(size_t)b * 1024 + m0 + t], redI[t]);
    }
}

// ---------------- Kernel 5: fused head = gemm3 + gemm4 -----------------------
__global__ __launch_bounds__(256) void fused_head(
    const unsigned short* __restrict__ Wb2, const unsigned short* __restrict__ Wb3,
    const float* __restrict__ mb0, const float* __restrict__ mb1,
    const unsigned short* __restrict__ gft, float* __restrict__ outp)
{
    __shared__ __align__(16) unsigned short As[256 * 40];
    __shared__ __align__(16) unsigned short Bs[64 * 40];
    __shared__ __align__(16) unsigned short H[64 * 264];
    __shared__ float b0s[256];
    __shared__ float b1s[128];

    const int t = threadIdx.x;
    const int n0 = blockIdx.x * 64;
    const int b = blockIdx.y;
    b0s[t] = mb0[t];
    if (t < 128) b1s[t] = mb1[t];

    const int wave = t >> 6, lane = t & 63, quad = lane >> 4, l15 = lane & 15;

    // ---- phase 1: C1[256m x 64n], K = 1024 ----
    const unsigned short* Ap = Wb2 + (size_t)t * 1024;
    const int bn = t >> 2, bq = t & 3;
    const unsigned short* Bp = gft + ((size_t)b * NPTS + n0) * 1024;

    floatx4 acc[16];
    #pragma unroll
    for (int i = 0; i < 16; ++i) acc[i] = (floatx4){0.f, 0.f, 0.f, 0.f};

    for (int kt = 0; kt < 32; ++kt) {
        const int k0 = kt << 5;
        uint4 a0 = *(const uint4*)(Ap + k0);
        uint4 a1 = *(const uint4*)(Ap + k0 + 8);
        uint4 a2 = *(const uint4*)(Ap + k0 + 16);
        uint4 a3 = *(const uint4*)(Ap + k0 + 24);
        uint4 bv = *(const uint4*)(Bp + (size_t)bn * 1024 + k0 + bq * 8);
        __syncthreads();
        *(uint4*)&As[t * 40 + 0]  = a0;
        *(uint4*)&As[t * 40 + 8]  = a1;
        *(uint4*)&As[t * 40 + 16] = a2;
        *(uint4*)&As[t * 40 + 24] = a3;
        *(uint4*)&Bs[bn * 40 + bq * 8] = bv;
        __syncthreads();
        short8 af[4], bfv[4];
        #pragma unroll
        for (int i = 0; i < 4; ++i)
            af[i] = *(const short8*)&As[(wave * 64 + i * 16 + l15) * 40 + quad * 8];
        #pragma unroll
        for (int j = 0; j < 4; ++j)
            bfv[j] = *(const short8*)&Bs[(j * 16 + l15) * 40 + quad * 8];
        #pragma unroll
        for (int i = 0; i < 4; ++i)
            #pragma unroll
            for (int j = 0; j < 4; ++j)
                acc[i * 4 + j] = __builtin_amdgcn_mfma_f32_16x16x32_bf16(
                    af[i], bfv[j], acc[i * 4 + j], 0, 0, 0);
    }
    #pragma unroll
    for (int i = 0; i < 4; ++i) {
        const int mbase = wave * 64 + i * 16 + quad * 4;
        #pragma unroll
        for (int j = 0; j < 4; ++j) {
            const int nl = j * 16 + l15;
            ushort4 pk;
            pk.x = f2bf(fmaxf(acc[i * 4 + j][0] + b0s[mbase + 0], 0.f));
            pk.y = f2bf(fmaxf(acc[i * 4 + j][1] + b0s[mbase + 1], 0.f));
            pk.z = f2bf(fmaxf(acc[i * 4 + j][2] + b0s[mbase + 2], 0.f));
            pk.w = f2bf(fmaxf(acc[i * 4 + j][3] + b0s[mbase + 3], 0.f));
            *(ushort4*)&H[nl * 264 + mbase] = pk;
        }
    }

    // ---- phase 2: C2[128m x 64n], K = 256 (B = H in LDS) ----
    floatx4 acc2[8];
    #pragma unroll
    for (int i = 0; i < 8; ++i) acc2[i] = (floatx4){0.f, 0.f, 0.f, 0.f};
    const int am2 = t & 127, ah = t >> 7;

    for (int kt = 0; kt < 8; ++kt) {
        const int k0 = kt << 5;
        uint4 a0 = *(const uint4*)(Wb3 + (size_t)am2 * 256 + k0 + ah * 16);
        uint4 a1 = *(const uint4*)(Wb3 + (size_t)am2 * 256 + k0 + ah * 16 + 8);
        __syncthreads();
        *(uint4*)&As[am2 * 40 + ah * 16]     = a0;
        *(uint4*)&As[am2 * 40 + ah * 16 + 8] = a1;
        __syncthreads();
        short8 af2[2], bf2[4];
        #pragma unroll
        for (int i = 0; i < 2; ++i)
            af2[i] = *(const short8*)&As[(wave * 32 + i * 16 + l15) * 40 + quad * 8];
        #pragma unroll
        for (int j = 0; j < 4; ++j)
            bf2[j] = *(const short8*)&H[(j * 16 + l15) * 264 + k0 + quad * 8];
        #pragma unroll
        for (int i = 0; i < 2; ++i)
            #pragma unroll
            for (int j = 0; j < 4; ++j)
                acc2[i * 4 + j] = __builtin_amdgcn_mfma_f32_16x16x32_bf16(
                    af2[i], bf2[j], acc2[i * 4 + j], 0, 0, 0);
    }
    #pragma unroll
    for (int i = 0; i < 2; ++i) {
        const int m2 = wave * 32 + i * 16 + quad * 4;
        #pragma unroll
        for (int j = 0; j < 4; ++j) {
            const int n = n0 + j * 16 + l15;
            float* o = outp + ((size_t)b * 128 + m2) * NPTS + n;
            o[0 * NPTS] = fmaxf(acc2[i * 4 + j][0] + b1s[m2 + 0], 0.f);
            o[1 * NPTS] = fmaxf(acc2[i * 4 + j][1] + b1s[m2 + 1], 0.f);
            o[2 * NPTS] = fmaxf(acc2[i * 4 + j][2] + b1s[m2 + 2], 0.f);
            o[3 * NPTS] = fmaxf(acc2[i * 4 + j][3] + b1s[m2 + 3], 0.f);
        }
    }
}

extern "C" void kernel_launch(void* const* d_in, const int* in_sizes, int n_in,
                              void* d_out, int out_size, void* d_ws, size_t ws_size,
                              hipStream_t stream)
{
    const float* x   = (const float*)d_in[0];
    const float* sW0 = (const float*)d_in[1];
    const float* sb0 = (const float*)d_in[2];
    const float* sW1 = (const float*)d_in[3];
    const float* sb1 = (const float*)d_in[4];
    const float* sW2 = (const float*)d_in[5];
    const float* sb2 = (const float*)d_in[6];
    const float* gW0 = (const float*)d_in[7];
    const float* gb0 = (const float*)d_in[8];
    const float* gW1 = (const float*)d_in[9];
    const float* gb1 = (const float*)d_in[10];
    const float* mW0 = (const float*)d_in[11];
    const float* mb0 = (const float*)d_in[12];
    const float* mW1 = (const float*)d_in[13];
    const float* mb1 = (const float*)d_in[14];
    float* outp = (float*)d_out;

    char* ws = (char*)d_ws;
    int*            idx     = (int*)(ws);                        // 2 MB
    float4*         pts4    = (float4*)(ws + 2097152u);          // 256 KB
    unsigned short* Wb0     = (unsigned short*)(ws + 2359296u);  // 192 KB  gW0 bf16
    unsigned short* Wb1     = (unsigned short*)(ws + 2555904u);  // 512 KB  gW1 bf16
    unsigned short* Wb2     = (unsigned short*)(ws + 3080192u);  // 512 KB  mW0 bf16
    unsigned short* Wb3     = (unsigned short*)(ws + 3604480u);  // 64 KB   mW1 bf16
    unsigned short* F       = (unsigned short*)(ws + 4194304u);  // 12.6 MB [b][n][384] bf16
    unsigned short* point_t = (unsigned short*)(ws + 18874368u); // 12.6 MB [b][n][384] bf16
    unsigned short* gf0t    = (unsigned short*)(ws + 33554432u); // 8.4 MB  [b][n][256] bf16
    unsigned short* gft     = (unsigned short*)(ws + 50331648u); // 33.6 MB [b][n][1024] bf16

    prep_all<<<dim3(2624), dim3(256), 0, stream>>>(
        x, pts4, gW0, gW1, mW0, mW1, Wb0, Wb1, Wb2, Wb3);
    knn_kernel12<<<dim3(16384), dim3(256), 0, stream>>>(pts4, idx);
    pointmlp_kernel<<<dim3(512, 3), dim3(256), 0, stream>>>(
        x, sW0, sb0, sW1, sb1, sW2, sb2, F);
    maxgather_bf16<<<dim3(16384), dim3(192), 0, stream>>>(F, idx, point_t);
    gemm_bf16<0><<<dim3(2, 32, 4), dim3(256), 0, stream>>>(
        Wb0, point_t, gb0, gf0t, nullptr, 256, 384);
    gemm_bf16<1><<<dim3(8, 32, 4), dim3(256), 0, stream>>>(
        Wb1, gf0t, gb1, gft, outp, 1024, 256);
    fused_head<<<dim3(64, 4), dim3(256), 0, stream>>>(
        Wb2, Wb3, mb0, mb1, gft, outp + 4096);
}